// Round 3
// baseline (242.385 us; speedup 1.0000x reference)
//
#include <hip/hip_runtime.h>

#define INV_N2 (1.0f/262144.0f)
#define HALF_INV (0.5f*INV_N2)
#define YT_B ((size_t)(264 * 512))    // Yt batch stride in float2

typedef unsigned u32x2 __attribute__((ext_vector_type(2)));
typedef float v2f __attribute__((ext_vector_type(2)));

__device__ __forceinline__ v2f v2(float a, float b) { v2f r; r.x = a; r.y = b; return r; }
__device__ __forceinline__ int brev9(int v) { return (int)(__brev((unsigned)v) >> 23); }
__device__ __forceinline__ float hsin(float rev) { return __builtin_amdgcn_sinf(rev); }
__device__ __forceinline__ float hcos(float rev) { return __builtin_amdgcn_cosf(rev); }

// ---------------- cross-lane exchange ----------------
template<int CTRL>
__device__ __forceinline__ float xdpp(float x) {
  int v = __float_as_int(x);
  return __int_as_float(__builtin_amdgcn_update_dpp(v, v, CTRL, 0xF, 0xF, true));
}
__device__ __forceinline__ float xs1(float x) { return xdpp<0xB1>(x); }   // quad_perm [1,0,3,2]
__device__ __forceinline__ float xs2(float x) { return xdpp<0x4E>(x); }   // quad_perm [2,3,0,1]
__device__ __forceinline__ float xs8(float x) { return xdpp<0x128>(x); }  // row_ror:8
__device__ __forceinline__ float xs4(float x) {
  return __int_as_float(__builtin_amdgcn_ds_swizzle(__float_as_int(x), 0x101F));
}
__device__ __forceinline__ void swp16(float x, float &lo, float &hi) {
#if __has_builtin(__builtin_amdgcn_permlane16_swap)
  u32x2 r = __builtin_amdgcn_permlane16_swap(__float_as_uint(x), __float_as_uint(x), false, false);
  lo = __uint_as_float(r[0]); hi = __uint_as_float(r[1]);
#else
  float p = __int_as_float(__builtin_amdgcn_ds_swizzle(__float_as_int(x), 0x401F));
  bool up = (threadIdx.x & 16) != 0;
  lo = up ? p : x; hi = up ? x : p;
#endif
}
__device__ __forceinline__ void swp32(float x, float &lo, float &hi) {
#if __has_builtin(__builtin_amdgcn_permlane32_swap)
  u32x2 r = __builtin_amdgcn_permlane32_swap(__float_as_uint(x), __float_as_uint(x), false, false);
  lo = __uint_as_float(r[0]); hi = __uint_as_float(r[1]);
#else
  float p = __shfl_xor(x, 32, 64);
  bool up = (threadIdx.x & 32) != 0;
  lo = up ? p : x; hi = up ? x : p;
#endif
}

// ---------------- per-lane stage twiddles ----------------
struct Tw { float c[8], s[8]; };
__device__ __forceinline__ Tw make_tw(int lane) {
  Tw t;
  float a0 = (float)lane        * (1.0f/512.0f);
  float a1 = (float)lane        * (1.0f/256.0f);
  float a2 = (float)lane        * (1.0f/128.0f);
  float a3 = (float)(lane & 31) * (1.0f/64.0f);
  float a4 = (float)(lane & 15) * (1.0f/32.0f);
  float a5 = (float)(lane & 7)  * (1.0f/16.0f);
  float a6 = (float)(lane & 3)  * (1.0f/8.0f);
  float a7 = (float)(lane & 1)  * (1.0f/4.0f);
  t.c[0]=hcos(a0); t.s[0]=hsin(a0); t.c[1]=hcos(a1); t.s[1]=hsin(a1);
  t.c[2]=hcos(a2); t.s[2]=hsin(a2); t.c[3]=hcos(a3); t.s[3]=hsin(a3);
  t.c[4]=hcos(a4); t.s[4]=hsin(a4); t.c[5]=hcos(a5); t.s[5]=hsin(a5);
  t.c[6]=hcos(a6); t.s[6]=hsin(a6); t.c[7]=hcos(a7); t.s[7]=hsin(a7);
  return t;
}

// ---------------- packed cross-lane stage macros (TWO independent FFTs) ----
// State: v2f Xr[8], Xi[8]; FFT0 = regs 0..3, FFT1 = regs 4..7.
// Element n = (2j+h)*64 + lane within each FFT (j = reg index mod 4).
#define FWD_PK_XS(S, XCHG, CC, SS) { \
  const bool up = (lane & (S)) != 0; \
  const float sg = up ? -1.0f : 1.0f; \
  const float wr = up ? (CC) : 1.0f; \
  const float wi = up ? -(SS) : 0.0f; \
  const v2f sgv = v2(sg,sg), wrv = v2(wr,wr), wiv = v2(wi,wi); \
  _Pragma("unroll") for (int j = 0; j < 8; ++j) { \
    v2f Rr = v2(XCHG(Xr[j].x), XCHG(Xr[j].y)); \
    v2f Ri = v2(XCHG(Xi[j].x), XCHG(Xi[j].y)); \
    v2f vr = sgv*Xr[j] + Rr; v2f vi = sgv*Xi[j] + Ri; \
    Xr[j] = vr*wrv - vi*wiv; Xi[j] = vr*wiv + vi*wrv; } }

#define FWD_PK_SW(S, SWP, CC, SS) { \
  const bool up = (lane & (S)) != 0; \
  const float sg = up ? -1.0f : 1.0f; \
  const float wr = up ? (CC) : 1.0f; \
  const float wi = up ? -(SS) : 0.0f; \
  const v2f sgv = v2(sg,sg), wrv = v2(wr,wr), wiv = v2(wi,wi); \
  _Pragma("unroll") for (int j = 0; j < 8; ++j) { \
    float l0,h0,l1,h1; \
    SWP(Xr[j].x,l0,h0); SWP(Xr[j].y,l1,h1); \
    v2f Lr = v2(l0,l1), Hr = v2(h0,h1); \
    SWP(Xi[j].x,l0,h0); SWP(Xi[j].y,l1,h1); \
    v2f Li = v2(l0,l1), Hi = v2(h0,h1); \
    v2f vr = sgv*Hr + Lr; v2f vi = sgv*Hi + Li; \
    Xr[j] = vr*wrv - vi*wiv; Xi[j] = vr*wiv + vi*wrv; } }

#define INV_PK_XS(S, XCHG, CC, SS) { \
  const bool up = (lane & (S)) != 0; \
  const float wr = up ? (CC) : 1.0f; \
  const float wi = up ? (SS) : 0.0f; \
  const float sg = up ? -1.0f : 1.0f; \
  const v2f sgv = v2(sg,sg), wrv = v2(wr,wr), wiv = v2(wi,wi); \
  _Pragma("unroll") for (int j = 0; j < 8; ++j) { \
    v2f Zr = Xr[j]*wrv - Xi[j]*wiv; \
    v2f Zi = Xr[j]*wiv + Xi[j]*wrv; \
    v2f Rr = v2(XCHG(Zr.x), XCHG(Zr.y)); \
    v2f Ri = v2(XCHG(Zi.x), XCHG(Zi.y)); \
    Xr[j] = sgv*Zr + Rr; Xi[j] = sgv*Zi + Ri; } }

#define INV_PK_SW(S, SWP, CC, SS) { \
  const bool up = (lane & (S)) != 0; \
  const float wr = up ? (CC) : 1.0f; \
  const float wi = up ? (SS) : 0.0f; \
  const float sg = up ? -1.0f : 1.0f; \
  const v2f sgv = v2(sg,sg), wrv = v2(wr,wr), wiv = v2(wi,wi); \
  _Pragma("unroll") for (int j = 0; j < 8; ++j) { \
    v2f Zr = Xr[j]*wrv - Xi[j]*wiv; \
    v2f Zi = Xr[j]*wiv + Xi[j]*wrv; \
    float l0,h0,l1,h1; \
    SWP(Zr.x,l0,h0); SWP(Zr.y,l1,h1); \
    v2f Lr = v2(l0,l1), Hr = v2(h0,h1); \
    SWP(Zi.x,l0,h0); SWP(Zi.y,l1,h1); \
    v2f Li = v2(l0,l1), Hi = v2(h0,h1); \
    Xr[j] = sgv*Hr + Lr; Xi[j] = sgv*Hi + Li; } }

// Forward DIF x2: natural in -> bit-reversed out, two independent FFTs.
__device__ __forceinline__ void wave_fft512_fwd2(v2f Xr[8], v2f Xi[8], int lane,
                                                 const Tw& t) {
  { // s=256: packed per-k twiddles; second pair uses (Ti0, -Tr0)
    const float c8 = 0.70710678118654752f;
    float wr = t.c[0], wi = -t.s[0];
    float w1r = c8*(wr + wi), w1i = c8*(wi - wr);
    v2f Tr0 = v2(wr, w1r), Ti0 = v2(wi, w1i);
    #pragma unroll
    for (int o = 0; o < 8; o += 4) {
      { v2f Sr = Xr[o]+Xr[o+2], Si = Xi[o]+Xi[o+2];
        v2f Dr = Xr[o]-Xr[o+2], Di = Xi[o]-Xi[o+2];
        Xr[o] = Sr; Xi[o] = Si;
        Xr[o+2] = Dr*Tr0 - Di*Ti0; Xi[o+2] = Dr*Ti0 + Di*Tr0; }
      { v2f Sr = Xr[o+1]+Xr[o+3], Si = Xi[o+1]+Xi[o+3];
        v2f Dr = Xr[o+1]-Xr[o+3], Di = Xi[o+1]-Xi[o+3];
        Xr[o+1] = Sr; Xi[o+1] = Si;
        Xr[o+3] = Dr*Ti0 + Di*Tr0; Xi[o+3] = Di*Ti0 - Dr*Tr0; }
    }
  }
  { // s=128
    v2f Tr = v2(t.c[1], -t.s[1]), Ti = v2(-t.s[1], -t.c[1]);
    #pragma unroll
    for (int j = 0; j < 8; j += 2) {
      v2f Sr = Xr[j]+Xr[j+1], Si = Xi[j]+Xi[j+1];
      v2f Dr = Xr[j]-Xr[j+1], Di = Xi[j]-Xi[j+1];
      Xr[j] = Sr; Xi[j] = Si;
      Xr[j+1] = Dr*Tr - Di*Ti; Xi[j+1] = Dr*Ti + Di*Tr;
    }
  }
  { // s=64: intra-pair, scalar
    float wr = t.c[2], wi = -t.s[2];
    #pragma unroll
    for (int j = 0; j < 8; ++j) {
      float sr = Xr[j].x + Xr[j].y, si = Xi[j].x + Xi[j].y;
      float dr = Xr[j].x - Xr[j].y, di = Xi[j].x - Xi[j].y;
      Xr[j] = v2(sr, dr*wr - di*wi);
      Xi[j] = v2(si, dr*wi + di*wr);
    }
  }
  FWD_PK_SW(32, swp32, t.c[3], t.s[3])
  FWD_PK_SW(16, swp16, t.c[4], t.s[4])
  FWD_PK_XS(8,  xs8,  t.c[5], t.s[5])
  FWD_PK_XS(4,  xs4,  t.c[6], t.s[6])
  FWD_PK_XS(2,  xs2,  t.c[7], t.s[7])
  { // s=1
    const float sg = (lane & 1) ? -1.0f : 1.0f;
    const v2f sgv = v2(sg, sg);
    #pragma unroll
    for (int j = 0; j < 8; ++j) {
      v2f Rr = v2(xs1(Xr[j].x), xs1(Xr[j].y));
      v2f Ri = v2(xs1(Xi[j].x), xs1(Xi[j].y));
      Xr[j] = sgv*Xr[j] + Rr; Xi[j] = sgv*Xi[j] + Ri;
    }
  }
}

// Inverse DIT x2: bit-reversed in -> natural out (unnormalized).
__device__ __forceinline__ void wave_fft512_inv2(v2f Xr[8], v2f Xi[8], int lane,
                                                 const Tw& t) {
  { // s=1
    const float sg = (lane & 1) ? -1.0f : 1.0f;
    const v2f sgv = v2(sg, sg);
    #pragma unroll
    for (int j = 0; j < 8; ++j) {
      v2f Rr = v2(xs1(Xr[j].x), xs1(Xr[j].y));
      v2f Ri = v2(xs1(Xi[j].x), xs1(Xi[j].y));
      Xr[j] = sgv*Xr[j] + Rr; Xi[j] = sgv*Xi[j] + Ri;
    }
  }
  INV_PK_XS(2,  xs2,  t.c[7], t.s[7])
  INV_PK_XS(4,  xs4,  t.c[6], t.s[6])
  INV_PK_XS(8,  xs8,  t.c[5], t.s[5])
  INV_PK_SW(16, swp16, t.c[4], t.s[4])
  INV_PK_SW(32, swp32, t.c[3], t.s[3])
  { // s=64: intra-pair, scalar
    float wr = t.c[2], wi = t.s[2];
    #pragma unroll
    for (int j = 0; j < 8; ++j) {
      float tr = Xr[j].y*wr - Xi[j].y*wi, ti = Xr[j].y*wi + Xi[j].y*wr;
      Xr[j] = v2(Xr[j].x + tr, Xr[j].x - tr);
      Xi[j] = v2(Xi[j].x + ti, Xi[j].x - ti);
    }
  }
  { // s=128
    v2f Tr = v2(t.c[1], -t.s[1]), Ti = v2(t.s[1], t.c[1]);
    #pragma unroll
    for (int j = 0; j < 8; j += 2) {
      v2f tr = Xr[j+1]*Tr - Xi[j+1]*Ti;
      v2f ti = Xr[j+1]*Ti + Xi[j+1]*Tr;
      Xr[j+1] = Xr[j] - tr; Xi[j+1] = Xi[j] - ti;
      Xr[j]   = Xr[j] + tr; Xi[j]   = Xi[j] + ti;
    }
  }
  { // s=256
    const float c8 = 0.70710678118654752f;
    float wr = t.c[0], wi = t.s[0];
    float w1r = c8*(wr - wi), w1i = c8*(wr + wi);
    v2f Tr0 = v2(wr, w1r), Ti0 = v2(wi, w1i);
    #pragma unroll
    for (int o = 0; o < 8; o += 4) {
      { v2f tr = Xr[o+2]*Tr0 - Xi[o+2]*Ti0;
        v2f ti = Xr[o+2]*Ti0 + Xi[o+2]*Tr0;
        Xr[o+2] = Xr[o] - tr; Xi[o+2] = Xi[o] - ti;
        Xr[o]   = Xr[o] + tr; Xi[o]   = Xi[o] + ti; }
      { v2f tr = -(Xr[o+3]*Ti0) - Xi[o+3]*Tr0;
        v2f ti = Xr[o+3]*Tr0 - Xi[o+3]*Ti0;
        Xr[o+3] = Xr[o+1] - tr; Xi[o+3] = Xi[o+1] - ti;
        Xr[o+1] = Xr[o+1] + tr; Xi[o+1] = Xi[o+1] + ti; }
    }
  }
}

// ---------------- kernels ----------------

// 4 real rows per wave (two packed FFTs); output TRANSPOSED: Yt[b][j][r].
// Block = 256 threads = 4 waves = 16 rows.
// Blocks >= 2048 instead perform the W scatter (independent work, fused to
// remove a serial dispatch: scatter writes W, FFT blocks write Yt — disjoint).
__global__ __launch_bounds__(256) void k_fwd_rows(const float* __restrict__ x,
                                                  float2* __restrict__ Yt,
                                                  const int4* __restrict__ idxx,
                                                  const int4* __restrict__ idxy,
                                                  const int4* __restrict__ cid,
                                                  int* __restrict__ W) {
  __shared__ float2 zc[8][517];                  // 33.1 KB; stride 517 -> f-slots 10 banks apart
  if (blockIdx.x >= 2048) {                      // ---- fused scatter blocks ----
    int p = (blockIdx.x - 2048) * 256 + threadIdx.x;   // 65536 threads, 4 points each
    int4 vx = idxx[p], vy = idxy[p], vc = cid[p];
    int p4 = p << 2;
    { int u = (vx.x + 256) & 511, v = (vy.x + 256) & 511;
      atomicMax(&W[u * 512 + v], ((p4 + 0) << 6) | vc.x); }
    { int u = (vx.y + 256) & 511, v = (vy.y + 256) & 511;
      atomicMax(&W[u * 512 + v], ((p4 + 1) << 6) | vc.y); }
    { int u = (vx.z + 256) & 511, v = (vy.z + 256) & 511;
      atomicMax(&W[u * 512 + v], ((p4 + 2) << 6) | vc.z); }
    { int u = (vx.w + 256) & 511, v = (vy.w + 256) & 511;
      atomicMax(&W[u * 512 + v], ((p4 + 3) << 6) | vc.w); }
    return;
  }
  int tid = threadIdx.x, w = tid >> 6, lane = tid & 63;
  int R0 = blockIdx.x * 16;
  int bb = R0 >> 9, r0 = R0 & 511;
  const float* r00 = x + (size_t)(R0 + 4 * w) * 512;   // FFT0: rows +0,+1; FFT1: +2,+3
  Tw t = make_tw(lane);
  v2f Xr[8], Xi[8];
  #pragma unroll
  for (int j = 0; j < 4; ++j) {
    Xr[j]   = v2(r00[(2*j)*64 + lane],        r00[(2*j+1)*64 + lane]);
    Xi[j]   = v2(r00[512 + (2*j)*64 + lane],  r00[512 + (2*j+1)*64 + lane]);
    Xr[4+j] = v2(r00[1024 + (2*j)*64 + lane], r00[1024 + (2*j+1)*64 + lane]);
    Xi[4+j] = v2(r00[1536 + (2*j)*64 + lane], r00[1536 + (2*j+1)*64 + lane]);
  }
  wave_fft512_fwd2(Xr, Xi, lane, t);
  #pragma unroll
  for (int q = 0; q < 4; ++q) {                  // b64 writes, lane-consecutive
    zc[2*w]  [(2*q)*64 + lane]   = make_float2(Xr[q].x,   Xi[q].x);
    zc[2*w]  [(2*q+1)*64 + lane] = make_float2(Xr[q].y,   Xi[q].y);
    zc[2*w+1][(2*q)*64 + lane]   = make_float2(Xr[4+q].x, Xi[4+q].x);
    zc[2*w+1][(2*q+1)*64 + lane] = make_float2(Xr[4+q].y, Xi[4+q].y);
  }
  __syncthreads();
  #pragma unroll
  for (int rep = 0; rep < 17; ++rep) {           // split + 128B-contiguous stores per column
    int e = rep * 256 + tid;
    int j = e >> 4, rr = e & 15;
    if (j < 257) {
      int f = rr >> 1;                           // FFT slot: rows (2f, 2f+1)
      int n2 = (j == 256) ? 1 : 2 * j;           // even bit-rev position for freq j
      int kf = brev9(n2);
      int m  = brev9((512 - kf) & 511);          // mirror position
      float2 Z = zc[f][n2];
      float2 M = zc[f][m];
      float2 o = (rr & 1)
        ? make_float2(0.5f*(Z.y + M.y), 0.5f*(M.x - Z.x))   // B (odd row)
        : make_float2(0.5f*(Z.x + M.x), 0.5f*(Z.y - M.y));  // A (even row)
      Yt[((size_t)bb * 264 + j) * 512 + r0 + rr] = o;
    }
  }
}

__device__ __forceinline__ int selc(int c) { return (c < 0) ? 127 : (c & 63); }

// Column FFT + symmetrized mask + inverse column FFT; 2 columns per wave, in-place.
// The pk pack step is inlined: 32 scattered W loads per thread (L2-resident 1MB)
// issued AFTER the Yt loads, consumed only after the forward FFT -> latency hidden.
// Loads unconditional (pads safe); only stores guarded (round-1 lesson).
__global__ __launch_bounds__(256) void k_cols(float2* __restrict__ Yt,
                                              const int* __restrict__ W,
                                              const float* __restrict__ pimp) {
  __shared__ float pilx[128];
  int tid = threadIdx.x;
  int b = blockIdx.x / 33, g = blockIdx.x % 33;
  if (tid < 128) pilx[tid] = (tid < 64) ? pimp[b * 64 + tid] * HALF_INV : HALF_INV;
  int w = tid >> 6, lane = tid & 63;
  int j0 = g * 8 + 2 * w;
  int j1 = j0 + 1;
  float2* col0 = Yt + ((size_t)b * 264 + j0) * 512;
  float2* col1 = col0 + 512;
  v2f Xr[8], Xi[8];
  #pragma unroll
  for (int q = 0; q < 4; ++q) {                  // coalesced column loads FIRST (FFT needs them)
    float2 a0 = col0[(2*q)*64 + lane], a1 = col0[(2*q+1)*64 + lane];
    float2 b0 = col1[(2*q)*64 + lane], b1 = col1[(2*q+1)*64 + lane];
    Xr[q]   = v2(a0.x, a1.x); Xi[q]   = v2(a0.y, a1.y);
    Xr[4+q] = v2(b0.x, b1.x); Xi[4+q] = v2(b0.y, b1.y);
  }
  // inline pack: per-column frequency index v (wave-uniform), then scattered W gathers
  int v0 = (j0 >= 256) ? 256 : brev9(2 * j0);
  int v1 = (j1 >= 256) ? 256 : brev9(2 * j1);
  int v0m = (512 - v0) & 511, v1m = (512 - v1) & 511;
  int pa[16], pb[16];
  #pragma unroll
  for (int e = 0; e < 8; ++e) {                  // entry n = e*64 + lane
    int u = brev9(e * 64 + lane), um = (512 - u) & 511;
    pa[e]     = W[u * 512 + v0];
    pb[e]     = W[um * 512 + v0m];
    pa[8 + e] = W[u * 512 + v1];
    pb[8 + e] = W[um * 512 + v1m];
  }
  Tw t = make_tw(lane);
  wave_fft512_fwd2(Xr, Xi, lane, t);
  __syncthreads();                               // pilx ready (hidden behind FFT)
  #pragma unroll
  for (int q = 0; q < 8; ++q) {                  // packed symmetrized mask (W loads landed)
    v2f mv = v2(pilx[selc(pa[2*q])]   + pilx[selc(pb[2*q])],
                pilx[selc(pa[2*q+1])] + pilx[selc(pb[2*q+1])]);
    Xr[q] *= mv; Xi[q] *= mv;
  }
  wave_fft512_inv2(Xr, Xi, lane, t);
  bool live0 = (j0 <= 256), live1 = (j1 <= 256);   // guard STORES only (end; latency-free)
  #pragma unroll
  for (int q = 0; q < 4; ++q) {
    if (live0) {
      col0[(2*q)*64 + lane]   = make_float2(Xr[q].x, Xi[q].x);
      col0[(2*q+1)*64 + lane] = make_float2(Xr[q].y, Xi[q].y);
    }
    if (live1) {
      col1[(2*q)*64 + lane]   = make_float2(Xr[4+q].x, Xi[4+q].x);
      col1[(2*q+1)*64 + lane] = make_float2(Xr[4+q].y, Xi[4+q].y);
    }
  }
}

// Hermitian merge folded into the load loop: C = A + iB is written directly
// to the complex tile at FFT input positions; FFT reads are b64 lane-consecutive.
__global__ __launch_bounds__(256) void k_inv_rows(const float2* __restrict__ Yt,
                                                  float* __restrict__ out) {
  __shared__ float2 zc[8][517];
  int tid = threadIdx.x, w = tid >> 6, lane = tid & 63;
  int R0 = blockIdx.x * 16;
  int bb = R0 >> 9, r0 = R0 & 511;
  #pragma unroll
  for (int rep = 0; rep < 9; ++rep) {            // 257*8 (j,f) items; 16B dwordx4 loads
    int e = rep * 256 + tid;
    int j = e >> 3, f = e & 7;
    if (j < 257) {
      const float2* src = &Yt[((size_t)bb * 264 + j) * 512 + r0 + 2 * f];
      float2 a = src[0], b = src[1];             // contiguous 16B -> dwordx4
      float2 ce = make_float2(a.x - b.y, a.y + b.x);     // s = +1 branch
      if (j == 0) {
        zc[f][0] = ce;
      } else if (j == 256) {
        zc[f][1] = ce;
      } else {
        zc[f][2*j] = ce;
        int po = brev9((512 - brev9(2*j)) & 511);        // odd mirror position
        zc[f][po] = make_float2(a.x + b.y, b.x - a.y);   // s = -1 branch
      }
    }
  }
  Tw t = make_tw(lane);
  __syncthreads();
  v2f Xr[8], Xi[8];
  #pragma unroll
  for (int q = 0; q < 4; ++q) {
    float2 c0 = zc[2*w]  [(2*q)*64 + lane];
    float2 c1 = zc[2*w]  [(2*q+1)*64 + lane];
    float2 d0 = zc[2*w+1][(2*q)*64 + lane];
    float2 d1 = zc[2*w+1][(2*q+1)*64 + lane];
    Xr[q]   = v2(c0.x, c1.x); Xi[q]   = v2(c0.y, c1.y);
    Xr[4+q] = v2(d0.x, d1.x); Xi[4+q] = v2(d0.y, d1.y);
  }
  wave_fft512_inv2(Xr, Xi, lane, t);
  float* orA0 = out + (size_t)(R0 + 4 * w) * 512;
  float* orB0 = orA0 + 512;
  float* orA1 = orA0 + 1024;
  float* orB1 = orA0 + 1536;
  #pragma unroll
  for (int q = 0; q < 4; ++q) {
    orA0[(2*q)*64 + lane]   = Xr[q].x;   orA0[(2*q+1)*64 + lane] = Xr[q].y;
    orB0[(2*q)*64 + lane]   = Xi[q].x;   orB0[(2*q+1)*64 + lane] = Xi[q].y;
    orA1[(2*q)*64 + lane]   = Xr[4+q].x; orA1[(2*q+1)*64 + lane] = Xr[4+q].y;
    orB1[(2*q)*64 + lane]   = Xi[4+q].x; orB1[(2*q+1)*64 + lane] = Xi[4+q].y;
  }
}

extern "C" void kernel_launch(void* const* d_in, const int* in_sizes, int n_in,
                              void* d_out, int out_size, void* d_ws, size_t ws_size,
                              hipStream_t stream) {
  const float* x    = (const float*)d_in[0];
  const float* pimp = (const float*)d_in[1];
  const int* idxx   = (const int*)d_in[2];
  const int* idxy   = (const int*)d_in[3];
  const int* cid    = (const int*)d_in[4];

  float2* Yt = (float2*)d_ws;                                    // 69.2 MB
  int* W  = (int*)((char*)d_ws + (size_t)64 * YT_B * sizeof(float2)); // 1 MB

  hipMemsetAsync(W, 0xFF, 512 * 512 * sizeof(int), stream);
  k_fwd_rows <<<2048 + 256, 256, 0, stream>>>(x, Yt,
                                              (const int4*)idxx, (const int4*)idxy,
                                              (const int4*)cid, W);
  k_cols     <<<64 * 33, 256, 0, stream>>>(Yt, W, pimp);
  k_inv_rows <<<2048, 256, 0, stream>>>(Yt, (float*)d_out);
}

// Round 4
// 194.593 us; speedup vs baseline: 1.2456x; 1.2456x over previous
//
#include <hip/hip_runtime.h>

#define INV_N2 (1.0f/262144.0f)
#define HALF_INV (0.5f*INV_N2)
#define YT_B ((size_t)(264 * 512))    // Yt batch stride in float2

typedef unsigned u32x2 __attribute__((ext_vector_type(2)));
typedef float v2f __attribute__((ext_vector_type(2)));

__device__ __forceinline__ v2f v2(float a, float b) { v2f r; r.x = a; r.y = b; return r; }
__device__ __forceinline__ int brev9(int v) { return (int)(__brev((unsigned)v) >> 23); }
__device__ __forceinline__ float hsin(float rev) { return __builtin_amdgcn_sinf(rev); }
__device__ __forceinline__ float hcos(float rev) { return __builtin_amdgcn_cosf(rev); }

// ---------------- cross-lane exchange ----------------
template<int CTRL>
__device__ __forceinline__ float xdpp(float x) {
  int v = __float_as_int(x);
  return __int_as_float(__builtin_amdgcn_update_dpp(v, v, CTRL, 0xF, 0xF, true));
}
__device__ __forceinline__ float xs1(float x) { return xdpp<0xB1>(x); }   // quad_perm [1,0,3,2]
__device__ __forceinline__ float xs2(float x) { return xdpp<0x4E>(x); }   // quad_perm [2,3,0,1]
__device__ __forceinline__ float xs8(float x) { return xdpp<0x128>(x); }  // row_ror:8
__device__ __forceinline__ float xs4(float x) {
  return __int_as_float(__builtin_amdgcn_ds_swizzle(__float_as_int(x), 0x101F));
}
__device__ __forceinline__ void swp16(float x, float &lo, float &hi) {
#if __has_builtin(__builtin_amdgcn_permlane16_swap)
  u32x2 r = __builtin_amdgcn_permlane16_swap(__float_as_uint(x), __float_as_uint(x), false, false);
  lo = __uint_as_float(r[0]); hi = __uint_as_float(r[1]);
#else
  float p = __int_as_float(__builtin_amdgcn_ds_swizzle(__float_as_int(x), 0x401F));
  bool up = (threadIdx.x & 16) != 0;
  lo = up ? p : x; hi = up ? x : p;
#endif
}
__device__ __forceinline__ void swp32(float x, float &lo, float &hi) {
#if __has_builtin(__builtin_amdgcn_permlane32_swap)
  u32x2 r = __builtin_amdgcn_permlane32_swap(__float_as_uint(x), __float_as_uint(x), false, false);
  lo = __uint_as_float(r[0]); hi = __uint_as_float(r[1]);
#else
  float p = __shfl_xor(x, 32, 64);
  bool up = (threadIdx.x & 32) != 0;
  lo = up ? p : x; hi = up ? x : p;
#endif
}

// ---------------- per-lane stage twiddles ----------------
struct Tw { float c[8], s[8]; };
__device__ __forceinline__ Tw make_tw(int lane) {
  Tw t;
  float a0 = (float)lane        * (1.0f/512.0f);
  float a1 = (float)lane        * (1.0f/256.0f);
  float a2 = (float)lane        * (1.0f/128.0f);
  float a3 = (float)(lane & 31) * (1.0f/64.0f);
  float a4 = (float)(lane & 15) * (1.0f/32.0f);
  float a5 = (float)(lane & 7)  * (1.0f/16.0f);
  float a6 = (float)(lane & 3)  * (1.0f/8.0f);
  float a7 = (float)(lane & 1)  * (1.0f/4.0f);
  t.c[0]=hcos(a0); t.s[0]=hsin(a0); t.c[1]=hcos(a1); t.s[1]=hsin(a1);
  t.c[2]=hcos(a2); t.s[2]=hsin(a2); t.c[3]=hcos(a3); t.s[3]=hsin(a3);
  t.c[4]=hcos(a4); t.s[4]=hsin(a4); t.c[5]=hcos(a5); t.s[5]=hsin(a5);
  t.c[6]=hcos(a6); t.s[6]=hsin(a6); t.c[7]=hcos(a7); t.s[7]=hsin(a7);
  return t;
}

// ---------------- packed cross-lane stage macros (TWO independent FFTs) ----
// State: v2f Xr[8], Xi[8]; FFT0 = regs 0..3, FFT1 = regs 4..7.
// Element n = (2j+h)*64 + lane within each FFT (j = reg index mod 4).
#define FWD_PK_XS(S, XCHG, CC, SS) { \
  const bool up = (lane & (S)) != 0; \
  const float sg = up ? -1.0f : 1.0f; \
  const float wr = up ? (CC) : 1.0f; \
  const float wi = up ? -(SS) : 0.0f; \
  const v2f sgv = v2(sg,sg), wrv = v2(wr,wr), wiv = v2(wi,wi); \
  _Pragma("unroll") for (int j = 0; j < 8; ++j) { \
    v2f Rr = v2(XCHG(Xr[j].x), XCHG(Xr[j].y)); \
    v2f Ri = v2(XCHG(Xi[j].x), XCHG(Xi[j].y)); \
    v2f vr = sgv*Xr[j] + Rr; v2f vi = sgv*Xi[j] + Ri; \
    Xr[j] = vr*wrv - vi*wiv; Xi[j] = vr*wiv + vi*wrv; } }

#define FWD_PK_SW(S, SWP, CC, SS) { \
  const bool up = (lane & (S)) != 0; \
  const float sg = up ? -1.0f : 1.0f; \
  const float wr = up ? (CC) : 1.0f; \
  const float wi = up ? -(SS) : 0.0f; \
  const v2f sgv = v2(sg,sg), wrv = v2(wr,wr), wiv = v2(wi,wi); \
  _Pragma("unroll") for (int j = 0; j < 8; ++j) { \
    float l0,h0,l1,h1; \
    SWP(Xr[j].x,l0,h0); SWP(Xr[j].y,l1,h1); \
    v2f Lr = v2(l0,l1), Hr = v2(h0,h1); \
    SWP(Xi[j].x,l0,h0); SWP(Xi[j].y,l1,h1); \
    v2f Li = v2(l0,l1), Hi = v2(h0,h1); \
    v2f vr = sgv*Hr + Lr; v2f vi = sgv*Hi + Li; \
    Xr[j] = vr*wrv - vi*wiv; Xi[j] = vr*wiv + vi*wrv; } }

#define INV_PK_XS(S, XCHG, CC, SS) { \
  const bool up = (lane & (S)) != 0; \
  const float wr = up ? (CC) : 1.0f; \
  const float wi = up ? (SS) : 0.0f; \
  const float sg = up ? -1.0f : 1.0f; \
  const v2f sgv = v2(sg,sg), wrv = v2(wr,wr), wiv = v2(wi,wi); \
  _Pragma("unroll") for (int j = 0; j < 8; ++j) { \
    v2f Zr = Xr[j]*wrv - Xi[j]*wiv; \
    v2f Zi = Xr[j]*wiv + Xi[j]*wrv; \
    v2f Rr = v2(XCHG(Zr.x), XCHG(Zr.y)); \
    v2f Ri = v2(XCHG(Zi.x), XCHG(Zi.y)); \
    Xr[j] = sgv*Zr + Rr; Xi[j] = sgv*Zi + Ri; } }

#define INV_PK_SW(S, SWP, CC, SS) { \
  const bool up = (lane & (S)) != 0; \
  const float wr = up ? (CC) : 1.0f; \
  const float wi = up ? (SS) : 0.0f; \
  const float sg = up ? -1.0f : 1.0f; \
  const v2f sgv = v2(sg,sg), wrv = v2(wr,wr), wiv = v2(wi,wi); \
  _Pragma("unroll") for (int j = 0; j < 8; ++j) { \
    v2f Zr = Xr[j]*wrv - Xi[j]*wiv; \
    v2f Zi = Xr[j]*wiv + Xi[j]*wrv; \
    float l0,h0,l1,h1; \
    SWP(Zr.x,l0,h0); SWP(Zr.y,l1,h1); \
    v2f Lr = v2(l0,l1), Hr = v2(h0,h1); \
    SWP(Zi.x,l0,h0); SWP(Zi.y,l1,h1); \
    v2f Li = v2(l0,l1), Hi = v2(h0,h1); \
    Xr[j] = sgv*Hr + Lr; Xi[j] = sgv*Hi + Li; } }

// Forward DIF x2: natural in -> bit-reversed out, two independent FFTs.
__device__ __forceinline__ void wave_fft512_fwd2(v2f Xr[8], v2f Xi[8], int lane,
                                                 const Tw& t) {
  { // s=256: packed per-k twiddles; second pair uses (Ti0, -Tr0)
    const float c8 = 0.70710678118654752f;
    float wr = t.c[0], wi = -t.s[0];
    float w1r = c8*(wr + wi), w1i = c8*(wi - wr);
    v2f Tr0 = v2(wr, w1r), Ti0 = v2(wi, w1i);
    #pragma unroll
    for (int o = 0; o < 8; o += 4) {
      { v2f Sr = Xr[o]+Xr[o+2], Si = Xi[o]+Xi[o+2];
        v2f Dr = Xr[o]-Xr[o+2], Di = Xi[o]-Xi[o+2];
        Xr[o] = Sr; Xi[o] = Si;
        Xr[o+2] = Dr*Tr0 - Di*Ti0; Xi[o+2] = Dr*Ti0 + Di*Tr0; }
      { v2f Sr = Xr[o+1]+Xr[o+3], Si = Xi[o+1]+Xi[o+3];
        v2f Dr = Xr[o+1]-Xr[o+3], Di = Xi[o+1]-Xi[o+3];
        Xr[o+1] = Sr; Xi[o+1] = Si;
        Xr[o+3] = Dr*Ti0 + Di*Tr0; Xi[o+3] = Di*Ti0 - Dr*Tr0; }
    }
  }
  { // s=128
    v2f Tr = v2(t.c[1], -t.s[1]), Ti = v2(-t.s[1], -t.c[1]);
    #pragma unroll
    for (int j = 0; j < 8; j += 2) {
      v2f Sr = Xr[j]+Xr[j+1], Si = Xi[j]+Xi[j+1];
      v2f Dr = Xr[j]-Xr[j+1], Di = Xi[j]-Xi[j+1];
      Xr[j] = Sr; Xi[j] = Si;
      Xr[j+1] = Dr*Tr - Di*Ti; Xi[j+1] = Dr*Ti + Di*Tr;
    }
  }
  { // s=64: intra-pair, scalar
    float wr = t.c[2], wi = -t.s[2];
    #pragma unroll
    for (int j = 0; j < 8; ++j) {
      float sr = Xr[j].x + Xr[j].y, si = Xi[j].x + Xi[j].y;
      float dr = Xr[j].x - Xr[j].y, di = Xi[j].x - Xi[j].y;
      Xr[j] = v2(sr, dr*wr - di*wi);
      Xi[j] = v2(si, dr*wi + di*wr);
    }
  }
  FWD_PK_SW(32, swp32, t.c[3], t.s[3])
  FWD_PK_SW(16, swp16, t.c[4], t.s[4])
  FWD_PK_XS(8,  xs8,  t.c[5], t.s[5])
  FWD_PK_XS(4,  xs4,  t.c[6], t.s[6])
  FWD_PK_XS(2,  xs2,  t.c[7], t.s[7])
  { // s=1
    const float sg = (lane & 1) ? -1.0f : 1.0f;
    const v2f sgv = v2(sg, sg);
    #pragma unroll
    for (int j = 0; j < 8; ++j) {
      v2f Rr = v2(xs1(Xr[j].x), xs1(Xr[j].y));
      v2f Ri = v2(xs1(Xi[j].x), xs1(Xi[j].y));
      Xr[j] = sgv*Xr[j] + Rr; Xi[j] = sgv*Xi[j] + Ri;
    }
  }
}

// Inverse DIT x2: bit-reversed in -> natural out (unnormalized).
__device__ __forceinline__ void wave_fft512_inv2(v2f Xr[8], v2f Xi[8], int lane,
                                                 const Tw& t) {
  { // s=1
    const float sg = (lane & 1) ? -1.0f : 1.0f;
    const v2f sgv = v2(sg, sg);
    #pragma unroll
    for (int j = 0; j < 8; ++j) {
      v2f Rr = v2(xs1(Xr[j].x), xs1(Xr[j].y));
      v2f Ri = v2(xs1(Xi[j].x), xs1(Xi[j].y));
      Xr[j] = sgv*Xr[j] + Rr; Xi[j] = sgv*Xi[j] + Ri;
    }
  }
  INV_PK_XS(2,  xs2,  t.c[7], t.s[7])
  INV_PK_XS(4,  xs4,  t.c[6], t.s[6])
  INV_PK_XS(8,  xs8,  t.c[5], t.s[5])
  INV_PK_SW(16, swp16, t.c[4], t.s[4])
  INV_PK_SW(32, swp32, t.c[3], t.s[3])
  { // s=64: intra-pair, scalar
    float wr = t.c[2], wi = t.s[2];
    #pragma unroll
    for (int j = 0; j < 8; ++j) {
      float tr = Xr[j].y*wr - Xi[j].y*wi, ti = Xr[j].y*wi + Xi[j].y*wr;
      Xr[j] = v2(Xr[j].x + tr, Xr[j].x - tr);
      Xi[j] = v2(Xi[j].x + ti, Xi[j].x - ti);
    }
  }
  { // s=128
    v2f Tr = v2(t.c[1], -t.s[1]), Ti = v2(t.s[1], t.c[1]);
    #pragma unroll
    for (int j = 0; j < 8; j += 2) {
      v2f tr = Xr[j+1]*Tr - Xi[j+1]*Ti;
      v2f ti = Xr[j+1]*Ti + Xi[j+1]*Tr;
      Xr[j+1] = Xr[j] - tr; Xi[j+1] = Xi[j] - ti;
      Xr[j]   = Xr[j] + tr; Xi[j]   = Xi[j] + ti;
    }
  }
  { // s=256
    const float c8 = 0.70710678118654752f;
    float wr = t.c[0], wi = t.s[0];
    float w1r = c8*(wr - wi), w1i = c8*(wr + wi);
    v2f Tr0 = v2(wr, w1r), Ti0 = v2(wi, w1i);
    #pragma unroll
    for (int o = 0; o < 8; o += 4) {
      { v2f tr = Xr[o+2]*Tr0 - Xi[o+2]*Ti0;
        v2f ti = Xr[o+2]*Ti0 + Xi[o+2]*Tr0;
        Xr[o+2] = Xr[o] - tr; Xi[o+2] = Xi[o] - ti;
        Xr[o]   = Xr[o] + tr; Xi[o]   = Xi[o] + ti; }
      { v2f tr = -(Xr[o+3]*Ti0) - Xi[o+3]*Tr0;
        v2f ti = Xr[o+3]*Tr0 - Xi[o+3]*Ti0;
        Xr[o+3] = Xr[o+1] - tr; Xi[o+3] = Xi[o+1] - ti;
        Xr[o+1] = Xr[o+1] + tr; Xi[o+1] = Xi[o+1] + ti; }
    }
  }
}

// ---------------- kernels ----------------

// pk pack: one-time gather of W into the coalesced per-column mask table.
// Amortized across all 64 batches (round-3 lesson: per-block re-gather in
// k_cols = 64x redundant uncoalesced L2 transactions, 2x slower k_cols).
__global__ void k_pack(const int* __restrict__ W, int* __restrict__ pk) {
  int idx = blockIdx.x * 256 + threadIdx.x;
  if (idx >= 264 * 512) return;
  int j = idx >> 9, n = idx & 511;
  int out = (127 << 7) | 127;
  if (j < 257) {
    int v = (j == 256) ? 256 : brev9(2 * j);
    int u = brev9(n);
    int c1 = W[u * 512 + v];
    int c2 = W[((512 - u) & 511) * 512 + ((512 - v) & 511)];
    int a = (c1 < 0) ? 127 : (c1 & 63);
    int b = (c2 < 0) ? 127 : (c2 & 63);
    out = (b << 7) | a;
  }
  pk[j * 512 + n] = out;
}

// 4 real rows per wave (two packed FFTs); output TRANSPOSED: Yt[b][j][r].
// Block = 256 threads = 4 waves = 16 rows.
// Blocks >= 2048 instead perform the W scatter (independent work, fused to
// remove a serial dispatch: scatter writes W, FFT blocks write Yt — disjoint).
__global__ __launch_bounds__(256) void k_fwd_rows(const float* __restrict__ x,
                                                  float2* __restrict__ Yt,
                                                  const int4* __restrict__ idxx,
                                                  const int4* __restrict__ idxy,
                                                  const int4* __restrict__ cid,
                                                  int* __restrict__ W) {
  __shared__ float2 zc[8][517];                  // 33.1 KB; stride 517 -> f-slots 10 banks apart
  if (blockIdx.x >= 2048) {                      // ---- fused scatter blocks ----
    int p = (blockIdx.x - 2048) * 256 + threadIdx.x;   // 65536 threads, 4 points each
    int4 vx = idxx[p], vy = idxy[p], vc = cid[p];
    int p4 = p << 2;
    { int u = (vx.x + 256) & 511, v = (vy.x + 256) & 511;
      atomicMax(&W[u * 512 + v], ((p4 + 0) << 6) | vc.x); }
    { int u = (vx.y + 256) & 511, v = (vy.y + 256) & 511;
      atomicMax(&W[u * 512 + v], ((p4 + 1) << 6) | vc.y); }
    { int u = (vx.z + 256) & 511, v = (vy.z + 256) & 511;
      atomicMax(&W[u * 512 + v], ((p4 + 2) << 6) | vc.z); }
    { int u = (vx.w + 256) & 511, v = (vy.w + 256) & 511;
      atomicMax(&W[u * 512 + v], ((p4 + 3) << 6) | vc.w); }
    return;
  }
  int tid = threadIdx.x, w = tid >> 6, lane = tid & 63;
  int R0 = blockIdx.x * 16;
  int bb = R0 >> 9, r0 = R0 & 511;
  const float* r00 = x + (size_t)(R0 + 4 * w) * 512;   // FFT0: rows +0,+1; FFT1: +2,+3
  Tw t = make_tw(lane);
  v2f Xr[8], Xi[8];
  #pragma unroll
  for (int j = 0; j < 4; ++j) {
    Xr[j]   = v2(r00[(2*j)*64 + lane],        r00[(2*j+1)*64 + lane]);
    Xi[j]   = v2(r00[512 + (2*j)*64 + lane],  r00[512 + (2*j+1)*64 + lane]);
    Xr[4+j] = v2(r00[1024 + (2*j)*64 + lane], r00[1024 + (2*j+1)*64 + lane]);
    Xi[4+j] = v2(r00[1536 + (2*j)*64 + lane], r00[1536 + (2*j+1)*64 + lane]);
  }
  wave_fft512_fwd2(Xr, Xi, lane, t);
  #pragma unroll
  for (int q = 0; q < 4; ++q) {                  // b64 writes, lane-consecutive
    zc[2*w]  [(2*q)*64 + lane]   = make_float2(Xr[q].x,   Xi[q].x);
    zc[2*w]  [(2*q+1)*64 + lane] = make_float2(Xr[q].y,   Xi[q].y);
    zc[2*w+1][(2*q)*64 + lane]   = make_float2(Xr[4+q].x, Xi[4+q].x);
    zc[2*w+1][(2*q+1)*64 + lane] = make_float2(Xr[4+q].y, Xi[4+q].y);
  }
  __syncthreads();
  #pragma unroll
  for (int rep = 0; rep < 17; ++rep) {           // split + 128B-contiguous stores per column
    int e = rep * 256 + tid;
    int j = e >> 4, rr = e & 15;
    if (j < 257) {
      int f = rr >> 1;                           // FFT slot: rows (2f, 2f+1)
      int n2 = (j == 256) ? 1 : 2 * j;           // even bit-rev position for freq j
      int kf = brev9(n2);
      int m  = brev9((512 - kf) & 511);          // mirror position
      float2 Z = zc[f][n2];
      float2 M = zc[f][m];
      float2 o = (rr & 1)
        ? make_float2(0.5f*(Z.y + M.y), 0.5f*(M.x - Z.x))   // B (odd row)
        : make_float2(0.5f*(Z.x + M.x), 0.5f*(Z.y - M.y));  // A (even row)
      Yt[((size_t)bb * 264 + j) * 512 + r0 + rr] = o;
    }
  }
}

// Column FFT + symmetrized mask + inverse column FFT; 2 columns per wave, in-place.
// Loads unconditional (pads safe; round-1 lesson: guarded loads serialize the
// burst). Stores guarded. pk read coalesced (round-3 lesson: no per-block gather).
__global__ __launch_bounds__(256) void k_cols(float2* __restrict__ Yt,
                                              const int* __restrict__ pk,
                                              const float* __restrict__ pimp) {
  __shared__ float pilx[128];
  int tid = threadIdx.x;
  int b = blockIdx.x / 33, g = blockIdx.x % 33;
  if (tid < 128) pilx[tid] = (tid < 64) ? pimp[b * 64 + tid] * HALF_INV : HALF_INV;
  int w = tid >> 6, lane = tid & 63;
  int j0 = g * 8 + 2 * w;
  float2* col0 = Yt + ((size_t)b * 264 + j0) * 512;
  float2* col1 = col0 + 512;
  const int* cm0 = pk + j0 * 512;
  const int* cm1 = cm0 + 512;
  int pcm[16];
  v2f Xr[8], Xi[8];
  #pragma unroll
  for (int q = 0; q < 4; ++q) {                  // coalesced loads + pk prefetch (both cols)
    float2 a0 = col0[(2*q)*64 + lane], a1 = col0[(2*q+1)*64 + lane];
    float2 b0 = col1[(2*q)*64 + lane], b1 = col1[(2*q+1)*64 + lane];
    Xr[q]   = v2(a0.x, a1.x); Xi[q]   = v2(a0.y, a1.y);
    Xr[4+q] = v2(b0.x, b1.x); Xi[4+q] = v2(b0.y, b1.y);
    pcm[2*q]     = cm0[(2*q)*64 + lane];
    pcm[2*q+1]   = cm0[(2*q+1)*64 + lane];
    pcm[8+2*q]   = cm1[(2*q)*64 + lane];
    pcm[8+2*q+1] = cm1[(2*q+1)*64 + lane];
  }
  Tw t = make_tw(lane);
  wave_fft512_fwd2(Xr, Xi, lane, t);
  __syncthreads();                               // pilx ready (hidden behind FFT)
  #pragma unroll
  for (int q = 0; q < 8; ++q) {                  // packed symmetrized mask
    int p0 = pcm[2*q], p1 = pcm[2*q+1];
    v2f mv = v2(pilx[p0 & 127] + pilx[(p0 >> 7) & 127],
                pilx[p1 & 127] + pilx[(p1 >> 7) & 127]);
    Xr[q] *= mv; Xi[q] *= mv;
  }
  wave_fft512_inv2(Xr, Xi, lane, t);
  bool live0 = (j0 <= 256), live1 = (j0 + 1 <= 256);   // guard STORES only
  #pragma unroll
  for (int q = 0; q < 4; ++q) {
    if (live0) {
      col0[(2*q)*64 + lane]   = make_float2(Xr[q].x, Xi[q].x);
      col0[(2*q+1)*64 + lane] = make_float2(Xr[q].y, Xi[q].y);
    }
    if (live1) {
      col1[(2*q)*64 + lane]   = make_float2(Xr[4+q].x, Xi[4+q].x);
      col1[(2*q+1)*64 + lane] = make_float2(Xr[4+q].y, Xi[4+q].y);
    }
  }
}

// Hermitian merge folded into the load loop: C = A + iB is written directly
// to the complex tile at FFT input positions; FFT reads are b64 lane-consecutive.
__global__ __launch_bounds__(256) void k_inv_rows(const float2* __restrict__ Yt,
                                                  float* __restrict__ out) {
  __shared__ float2 zc[8][517];
  int tid = threadIdx.x, w = tid >> 6, lane = tid & 63;
  int R0 = blockIdx.x * 16;
  int bb = R0 >> 9, r0 = R0 & 511;
  #pragma unroll
  for (int rep = 0; rep < 9; ++rep) {            // 257*8 (j,f) items; 16B dwordx4 loads
    int e = rep * 256 + tid;
    int j = e >> 3, f = e & 7;
    if (j < 257) {
      const float2* src = &Yt[((size_t)bb * 264 + j) * 512 + r0 + 2 * f];
      float2 a = src[0], b = src[1];             // contiguous 16B -> dwordx4
      float2 ce = make_float2(a.x - b.y, a.y + b.x);     // s = +1 branch
      if (j == 0) {
        zc[f][0] = ce;
      } else if (j == 256) {
        zc[f][1] = ce;
      } else {
        zc[f][2*j] = ce;
        int po = brev9((512 - brev9(2*j)) & 511);        // odd mirror position
        zc[f][po] = make_float2(a.x + b.y, b.x - a.y);   // s = -1 branch
      }
    }
  }
  Tw t = make_tw(lane);
  __syncthreads();
  v2f Xr[8], Xi[8];
  #pragma unroll
  for (int q = 0; q < 4; ++q) {
    float2 c0 = zc[2*w]  [(2*q)*64 + lane];
    float2 c1 = zc[2*w]  [(2*q+1)*64 + lane];
    float2 d0 = zc[2*w+1][(2*q)*64 + lane];
    float2 d1 = zc[2*w+1][(2*q+1)*64 + lane];
    Xr[q]   = v2(c0.x, c1.x); Xi[q]   = v2(c0.y, c1.y);
    Xr[4+q] = v2(d0.x, d1.x); Xi[4+q] = v2(d0.y, d1.y);
  }
  wave_fft512_inv2(Xr, Xi, lane, t);
  float* orA0 = out + (size_t)(R0 + 4 * w) * 512;
  float* orB0 = orA0 + 512;
  float* orA1 = orA0 + 1024;
  float* orB1 = orA0 + 1536;
  #pragma unroll
  for (int q = 0; q < 4; ++q) {
    orA0[(2*q)*64 + lane]   = Xr[q].x;   orA0[(2*q+1)*64 + lane] = Xr[q].y;
    orB0[(2*q)*64 + lane]   = Xi[q].x;   orB0[(2*q+1)*64 + lane] = Xi[q].y;
    orA1[(2*q)*64 + lane]   = Xr[4+q].x; orA1[(2*q+1)*64 + lane] = Xr[4+q].y;
    orB1[(2*q)*64 + lane]   = Xi[4+q].x; orB1[(2*q+1)*64 + lane] = Xi[4+q].y;
  }
}

extern "C" void kernel_launch(void* const* d_in, const int* in_sizes, int n_in,
                              void* d_out, int out_size, void* d_ws, size_t ws_size,
                              hipStream_t stream) {
  const float* x    = (const float*)d_in[0];
  const float* pimp = (const float*)d_in[1];
  const int* idxx   = (const int*)d_in[2];
  const int* idxy   = (const int*)d_in[3];
  const int* cid    = (const int*)d_in[4];

  float2* Yt = (float2*)d_ws;                                    // 69.2 MB
  int* W  = (int*)((char*)d_ws + (size_t)64 * YT_B * sizeof(float2)); // 1 MB
  int* pk = W + 512 * 512;                                       // 0.54 MB

  hipMemsetAsync(W, 0xFF, 512 * 512 * sizeof(int), stream);
  k_fwd_rows <<<2048 + 256, 256, 0, stream>>>(x, Yt,
                                              (const int4*)idxx, (const int4*)idxy,
                                              (const int4*)cid, W);
  k_pack     <<<(264 * 512 + 255) / 256, 256, 0, stream>>>(W, pk);
  k_cols     <<<64 * 33, 256, 0, stream>>>(Yt, pk, pimp);
  k_inv_rows <<<2048, 256, 0, stream>>>(Yt, (float*)d_out);
}

// Round 5
// 190.262 us; speedup vs baseline: 1.2740x; 1.0228x over previous
//
#include <hip/hip_runtime.h>

#define INV_N2 (1.0f/262144.0f)
#define HALF_INV (0.5f*INV_N2)
#define YT_B ((size_t)(264 * 512))    // Yt batch stride in float2

typedef unsigned u32x2 __attribute__((ext_vector_type(2)));
typedef float v2f __attribute__((ext_vector_type(2)));

__device__ __forceinline__ v2f v2(float a, float b) { v2f r; r.x = a; r.y = b; return r; }
__device__ __forceinline__ int brev9(int v) { return (int)(__brev((unsigned)v) >> 23); }
__device__ __forceinline__ float hsin(float rev) { return __builtin_amdgcn_sinf(rev); }
__device__ __forceinline__ float hcos(float rev) { return __builtin_amdgcn_cosf(rev); }

// ---------------- cross-lane exchange ----------------
template<int CTRL>
__device__ __forceinline__ float xdpp(float x) {
  int v = __float_as_int(x);
  return __int_as_float(__builtin_amdgcn_update_dpp(v, v, CTRL, 0xF, 0xF, true));
}
__device__ __forceinline__ float xs1(float x) { return xdpp<0xB1>(x); }   // quad_perm [1,0,3,2]
__device__ __forceinline__ float xs2(float x) { return xdpp<0x4E>(x); }   // quad_perm [2,3,0,1]
__device__ __forceinline__ float xs8(float x) { return xdpp<0x128>(x); }  // row_ror:8
__device__ __forceinline__ float xs4(float x) {
  return __int_as_float(__builtin_amdgcn_ds_swizzle(__float_as_int(x), 0x101F));
}
__device__ __forceinline__ void swp16(float x, float &lo, float &hi) {
#if __has_builtin(__builtin_amdgcn_permlane16_swap)
  u32x2 r = __builtin_amdgcn_permlane16_swap(__float_as_uint(x), __float_as_uint(x), false, false);
  lo = __uint_as_float(r[0]); hi = __uint_as_float(r[1]);
#else
  float p = __int_as_float(__builtin_amdgcn_ds_swizzle(__float_as_int(x), 0x401F));
  bool up = (threadIdx.x & 16) != 0;
  lo = up ? p : x; hi = up ? x : p;
#endif
}
__device__ __forceinline__ void swp32(float x, float &lo, float &hi) {
#if __has_builtin(__builtin_amdgcn_permlane32_swap)
  u32x2 r = __builtin_amdgcn_permlane32_swap(__float_as_uint(x), __float_as_uint(x), false, false);
  lo = __uint_as_float(r[0]); hi = __uint_as_float(r[1]);
#else
  float p = __shfl_xor(x, 32, 64);
  bool up = (threadIdx.x & 32) != 0;
  lo = up ? p : x; hi = up ? x : p;
#endif
}

// ---------------- per-lane stage twiddles ----------------
struct Tw { float c[8], s[8]; };
__device__ __forceinline__ Tw make_tw(int lane) {
  Tw t;
  float a0 = (float)lane        * (1.0f/512.0f);
  float a1 = (float)lane        * (1.0f/256.0f);
  float a2 = (float)lane        * (1.0f/128.0f);
  float a3 = (float)(lane & 31) * (1.0f/64.0f);
  float a4 = (float)(lane & 15) * (1.0f/32.0f);
  float a5 = (float)(lane & 7)  * (1.0f/16.0f);
  float a6 = (float)(lane & 3)  * (1.0f/8.0f);
  float a7 = (float)(lane & 1)  * (1.0f/4.0f);
  t.c[0]=hcos(a0); t.s[0]=hsin(a0); t.c[1]=hcos(a1); t.s[1]=hsin(a1);
  t.c[2]=hcos(a2); t.s[2]=hsin(a2); t.c[3]=hcos(a3); t.s[3]=hsin(a3);
  t.c[4]=hcos(a4); t.s[4]=hsin(a4); t.c[5]=hcos(a5); t.s[5]=hsin(a5);
  t.c[6]=hcos(a6); t.s[6]=hsin(a6); t.c[7]=hcos(a7); t.s[7]=hsin(a7);
  return t;
}

// ---------------- packed cross-lane stage macros (TWO independent FFTs) ----
// State: v2f Xr[8], Xi[8]; FFT0 = regs 0..3, FFT1 = regs 4..7.
// Element n = (2j+h)*64 + lane within each FFT (j = reg index mod 4).
#define FWD_PK_XS(S, XCHG, CC, SS) { \
  const bool up = (lane & (S)) != 0; \
  const float sg = up ? -1.0f : 1.0f; \
  const float wr = up ? (CC) : 1.0f; \
  const float wi = up ? -(SS) : 0.0f; \
  const v2f sgv = v2(sg,sg), wrv = v2(wr,wr), wiv = v2(wi,wi); \
  _Pragma("unroll") for (int j = 0; j < 8; ++j) { \
    v2f Rr = v2(XCHG(Xr[j].x), XCHG(Xr[j].y)); \
    v2f Ri = v2(XCHG(Xi[j].x), XCHG(Xi[j].y)); \
    v2f vr = sgv*Xr[j] + Rr; v2f vi = sgv*Xi[j] + Ri; \
    Xr[j] = vr*wrv - vi*wiv; Xi[j] = vr*wiv + vi*wrv; } }

#define FWD_PK_SW(S, SWP, CC, SS) { \
  const bool up = (lane & (S)) != 0; \
  const float sg = up ? -1.0f : 1.0f; \
  const float wr = up ? (CC) : 1.0f; \
  const float wi = up ? -(SS) : 0.0f; \
  const v2f sgv = v2(sg,sg), wrv = v2(wr,wr), wiv = v2(wi,wi); \
  _Pragma("unroll") for (int j = 0; j < 8; ++j) { \
    float l0,h0,l1,h1; \
    SWP(Xr[j].x,l0,h0); SWP(Xr[j].y,l1,h1); \
    v2f Lr = v2(l0,l1), Hr = v2(h0,h1); \
    SWP(Xi[j].x,l0,h0); SWP(Xi[j].y,l1,h1); \
    v2f Li = v2(l0,l1), Hi = v2(h0,h1); \
    v2f vr = sgv*Hr + Lr; v2f vi = sgv*Hi + Li; \
    Xr[j] = vr*wrv - vi*wiv; Xi[j] = vr*wiv + vi*wrv; } }

#define INV_PK_XS(S, XCHG, CC, SS) { \
  const bool up = (lane & (S)) != 0; \
  const float wr = up ? (CC) : 1.0f; \
  const float wi = up ? (SS) : 0.0f; \
  const float sg = up ? -1.0f : 1.0f; \
  const v2f sgv = v2(sg,sg), wrv = v2(wr,wr), wiv = v2(wi,wi); \
  _Pragma("unroll") for (int j = 0; j < 8; ++j) { \
    v2f Zr = Xr[j]*wrv - Xi[j]*wiv; \
    v2f Zi = Xr[j]*wiv + Xi[j]*wrv; \
    v2f Rr = v2(XCHG(Zr.x), XCHG(Zr.y)); \
    v2f Ri = v2(XCHG(Zi.x), XCHG(Zi.y)); \
    Xr[j] = sgv*Zr + Rr; Xi[j] = sgv*Zi + Ri; } }

#define INV_PK_SW(S, SWP, CC, SS) { \
  const bool up = (lane & (S)) != 0; \
  const float wr = up ? (CC) : 1.0f; \
  const float wi = up ? (SS) : 0.0f; \
  const float sg = up ? -1.0f : 1.0f; \
  const v2f sgv = v2(sg,sg), wrv = v2(wr,wr), wiv = v2(wi,wi); \
  _Pragma("unroll") for (int j = 0; j < 8; ++j) { \
    v2f Zr = Xr[j]*wrv - Xi[j]*wiv; \
    v2f Zi = Xr[j]*wiv + Xi[j]*wrv; \
    float l0,h0,l1,h1; \
    SWP(Zr.x,l0,h0); SWP(Zr.y,l1,h1); \
    v2f Lr = v2(l0,l1), Hr = v2(h0,h1); \
    SWP(Zi.x,l0,h0); SWP(Zi.y,l1,h1); \
    v2f Li = v2(l0,l1), Hi = v2(h0,h1); \
    Xr[j] = sgv*Hr + Lr; Xi[j] = sgv*Hi + Li; } }

// Forward DIF x2: natural in -> bit-reversed out, two independent FFTs.
__device__ __forceinline__ void wave_fft512_fwd2(v2f Xr[8], v2f Xi[8], int lane,
                                                 const Tw& t) {
  { // s=256: packed per-k twiddles; second pair uses (Ti0, -Tr0)
    const float c8 = 0.70710678118654752f;
    float wr = t.c[0], wi = -t.s[0];
    float w1r = c8*(wr + wi), w1i = c8*(wi - wr);
    v2f Tr0 = v2(wr, w1r), Ti0 = v2(wi, w1i);
    #pragma unroll
    for (int o = 0; o < 8; o += 4) {
      { v2f Sr = Xr[o]+Xr[o+2], Si = Xi[o]+Xi[o+2];
        v2f Dr = Xr[o]-Xr[o+2], Di = Xi[o]-Xi[o+2];
        Xr[o] = Sr; Xi[o] = Si;
        Xr[o+2] = Dr*Tr0 - Di*Ti0; Xi[o+2] = Dr*Ti0 + Di*Tr0; }
      { v2f Sr = Xr[o+1]+Xr[o+3], Si = Xi[o+1]+Xi[o+3];
        v2f Dr = Xr[o+1]-Xr[o+3], Di = Xi[o+1]-Xi[o+3];
        Xr[o+1] = Sr; Xi[o+1] = Si;
        Xr[o+3] = Dr*Ti0 + Di*Tr0; Xi[o+3] = Di*Ti0 - Dr*Tr0; }
    }
  }
  { // s=128
    v2f Tr = v2(t.c[1], -t.s[1]), Ti = v2(-t.s[1], -t.c[1]);
    #pragma unroll
    for (int j = 0; j < 8; j += 2) {
      v2f Sr = Xr[j]+Xr[j+1], Si = Xi[j]+Xi[j+1];
      v2f Dr = Xr[j]-Xr[j+1], Di = Xi[j]-Xi[j+1];
      Xr[j] = Sr; Xi[j] = Si;
      Xr[j+1] = Dr*Tr - Di*Ti; Xi[j+1] = Dr*Ti + Di*Tr;
    }
  }
  { // s=64: intra-pair, scalar
    float wr = t.c[2], wi = -t.s[2];
    #pragma unroll
    for (int j = 0; j < 8; ++j) {
      float sr = Xr[j].x + Xr[j].y, si = Xi[j].x + Xi[j].y;
      float dr = Xr[j].x - Xr[j].y, di = Xi[j].x - Xi[j].y;
      Xr[j] = v2(sr, dr*wr - di*wi);
      Xi[j] = v2(si, dr*wi + di*wr);
    }
  }
  FWD_PK_SW(32, swp32, t.c[3], t.s[3])
  FWD_PK_SW(16, swp16, t.c[4], t.s[4])
  FWD_PK_XS(8,  xs8,  t.c[5], t.s[5])
  FWD_PK_XS(4,  xs4,  t.c[6], t.s[6])
  FWD_PK_XS(2,  xs2,  t.c[7], t.s[7])
  { // s=1
    const float sg = (lane & 1) ? -1.0f : 1.0f;
    const v2f sgv = v2(sg, sg);
    #pragma unroll
    for (int j = 0; j < 8; ++j) {
      v2f Rr = v2(xs1(Xr[j].x), xs1(Xr[j].y));
      v2f Ri = v2(xs1(Xi[j].x), xs1(Xi[j].y));
      Xr[j] = sgv*Xr[j] + Rr; Xi[j] = sgv*Xi[j] + Ri;
    }
  }
}

// Inverse DIT x2: bit-reversed in -> natural out (unnormalized).
__device__ __forceinline__ void wave_fft512_inv2(v2f Xr[8], v2f Xi[8], int lane,
                                                 const Tw& t) {
  { // s=1
    const float sg = (lane & 1) ? -1.0f : 1.0f;
    const v2f sgv = v2(sg, sg);
    #pragma unroll
    for (int j = 0; j < 8; ++j) {
      v2f Rr = v2(xs1(Xr[j].x), xs1(Xr[j].y));
      v2f Ri = v2(xs1(Xi[j].x), xs1(Xi[j].y));
      Xr[j] = sgv*Xr[j] + Rr; Xi[j] = sgv*Xi[j] + Ri;
    }
  }
  INV_PK_XS(2,  xs2,  t.c[7], t.s[7])
  INV_PK_XS(4,  xs4,  t.c[6], t.s[6])
  INV_PK_XS(8,  xs8,  t.c[5], t.s[5])
  INV_PK_SW(16, swp16, t.c[4], t.s[4])
  INV_PK_SW(32, swp32, t.c[3], t.s[3])
  { // s=64: intra-pair, scalar
    float wr = t.c[2], wi = t.s[2];
    #pragma unroll
    for (int j = 0; j < 8; ++j) {
      float tr = Xr[j].y*wr - Xi[j].y*wi, ti = Xr[j].y*wi + Xi[j].y*wr;
      Xr[j] = v2(Xr[j].x + tr, Xr[j].x - tr);
      Xi[j] = v2(Xi[j].x + ti, Xi[j].x - ti);
    }
  }
  { // s=128
    v2f Tr = v2(t.c[1], -t.s[1]), Ti = v2(t.s[1], t.c[1]);
    #pragma unroll
    for (int j = 0; j < 8; j += 2) {
      v2f tr = Xr[j+1]*Tr - Xi[j+1]*Ti;
      v2f ti = Xr[j+1]*Ti + Xi[j+1]*Tr;
      Xr[j+1] = Xr[j] - tr; Xi[j+1] = Xi[j] - ti;
      Xr[j]   = Xr[j] + tr; Xi[j]   = Xi[j] + ti;
    }
  }
  { // s=256
    const float c8 = 0.70710678118654752f;
    float wr = t.c[0], wi = t.s[0];
    float w1r = c8*(wr - wi), w1i = c8*(wr + wi);
    v2f Tr0 = v2(wr, w1r), Ti0 = v2(wi, w1i);
    #pragma unroll
    for (int o = 0; o < 8; o += 4) {
      { v2f tr = Xr[o+2]*Tr0 - Xi[o+2]*Ti0;
        v2f ti = Xr[o+2]*Ti0 + Xi[o+2]*Tr0;
        Xr[o+2] = Xr[o] - tr; Xi[o+2] = Xi[o] - ti;
        Xr[o]   = Xr[o] + tr; Xi[o]   = Xi[o] + ti; }
      { v2f tr = -(Xr[o+3]*Ti0) - Xi[o+3]*Tr0;
        v2f ti = Xr[o+3]*Tr0 - Xi[o+3]*Ti0;
        Xr[o+3] = Xr[o+1] - tr; Xi[o+3] = Xi[o+1] - ti;
        Xr[o+1] = Xr[o+1] + tr; Xi[o+1] = Xi[o+1] + ti; }
    }
  }
}

// ---------------- kernels ----------------

// pk pack: one-time gather of W into the coalesced per-column mask table.
// Amortized across all 64 batches (round-3 lesson: per-block re-gather in
// k_cols = 64x redundant uncoalesced L2 transactions, 2x slower k_cols).
__global__ void k_pack(const int* __restrict__ W, int* __restrict__ pk) {
  int idx = blockIdx.x * 256 + threadIdx.x;
  if (idx >= 264 * 512) return;
  int j = idx >> 9, n = idx & 511;
  int out = (127 << 7) | 127;
  if (j < 257) {
    int v = (j == 256) ? 256 : brev9(2 * j);
    int u = brev9(n);
    int c1 = W[u * 512 + v];
    int c2 = W[((512 - u) & 511) * 512 + ((512 - v) & 511)];
    int a = (c1 < 0) ? 127 : (c1 & 63);
    int b = (c2 < 0) ? 127 : (c2 & 63);
    out = (b << 7) | a;
  }
  pk[j * 512 + n] = out;
}

// 4 real rows per wave (two packed FFTs); output TRANSPOSED: Yt[b][j][r].
// Block = 256 threads = 4 waves = 16 rows.
// Blocks >= 2048 instead perform the W scatter (independent work, fused to
// remove a serial dispatch: scatter writes W, FFT blocks write Yt — disjoint).
__global__ __launch_bounds__(256) void k_fwd_rows(const float* __restrict__ x,
                                                  float2* __restrict__ Yt,
                                                  const int4* __restrict__ idxx,
                                                  const int4* __restrict__ idxy,
                                                  const int4* __restrict__ cid,
                                                  int* __restrict__ W) {
  __shared__ float2 zc[8][517];                  // 33.1 KB; stride 517 -> f-slots 10 banks apart
  if (blockIdx.x >= 2048) {                      // ---- fused scatter blocks ----
    int p = (blockIdx.x - 2048) * 256 + threadIdx.x;   // 65536 threads, 4 points each
    int4 vx = idxx[p], vy = idxy[p], vc = cid[p];
    int p4 = p << 2;
    { int u = (vx.x + 256) & 511, v = (vy.x + 256) & 511;
      atomicMax(&W[u * 512 + v], ((p4 + 0) << 6) | vc.x); }
    { int u = (vx.y + 256) & 511, v = (vy.y + 256) & 511;
      atomicMax(&W[u * 512 + v], ((p4 + 1) << 6) | vc.y); }
    { int u = (vx.z + 256) & 511, v = (vy.z + 256) & 511;
      atomicMax(&W[u * 512 + v], ((p4 + 2) << 6) | vc.z); }
    { int u = (vx.w + 256) & 511, v = (vy.w + 256) & 511;
      atomicMax(&W[u * 512 + v], ((p4 + 3) << 6) | vc.w); }
    return;
  }
  int tid = threadIdx.x, w = tid >> 6, lane = tid & 63;
  int R0 = blockIdx.x * 16;
  int bb = R0 >> 9, r0 = R0 & 511;
  const float* r00 = x + (size_t)(R0 + 4 * w) * 512;   // FFT0: rows +0,+1; FFT1: +2,+3
  Tw t = make_tw(lane);
  v2f Xr[8], Xi[8];
  #pragma unroll
  for (int j = 0; j < 4; ++j) {
    Xr[j]   = v2(r00[(2*j)*64 + lane],        r00[(2*j+1)*64 + lane]);
    Xi[j]   = v2(r00[512 + (2*j)*64 + lane],  r00[512 + (2*j+1)*64 + lane]);
    Xr[4+j] = v2(r00[1024 + (2*j)*64 + lane], r00[1024 + (2*j+1)*64 + lane]);
    Xi[4+j] = v2(r00[1536 + (2*j)*64 + lane], r00[1536 + (2*j+1)*64 + lane]);
  }
  wave_fft512_fwd2(Xr, Xi, lane, t);
  #pragma unroll
  for (int q = 0; q < 4; ++q) {                  // b64 writes, lane-consecutive
    zc[2*w]  [(2*q)*64 + lane]   = make_float2(Xr[q].x,   Xi[q].x);
    zc[2*w]  [(2*q+1)*64 + lane] = make_float2(Xr[q].y,   Xi[q].y);
    zc[2*w+1][(2*q)*64 + lane]   = make_float2(Xr[4+q].x, Xi[4+q].x);
    zc[2*w+1][(2*q+1)*64 + lane] = make_float2(Xr[4+q].y, Xi[4+q].y);
  }
  __syncthreads();
  #pragma unroll
  for (int rep = 0; rep < 17; ++rep) {           // split + 128B-contiguous stores per column
    int e = rep * 256 + tid;
    int j = e >> 4, rr = e & 15;
    if (j < 257) {
      int f = rr >> 1;                           // FFT slot: rows (2f, 2f+1)
      int n2 = (j == 256) ? 1 : 2 * j;           // even bit-rev position for freq j
      int kf = brev9(n2);
      int m  = brev9((512 - kf) & 511);          // mirror position
      float2 Z = zc[f][n2];
      float2 M = zc[f][m];
      float2 o = (rr & 1)
        ? make_float2(0.5f*(Z.y + M.y), 0.5f*(M.x - Z.x))   // B (odd row)
        : make_float2(0.5f*(Z.x + M.x), 0.5f*(Z.y - M.y));  // A (even row)
      Yt[((size_t)bb * 264 + j) * 512 + r0 + rr] = o;
    }
  }
}

// Column FFT + symmetrized mask + inverse column FFT; 2 columns per wave, in-place.
// Round-4 lesson: identical source recompiled to a 52-VGPR occupancy-greedy
// schedule that serialized the 32-load burst (57 us, VALUBusy 37%). Pin it:
// (a) launch_bounds(256,2) gives the allocator a 128-VGPR budget,
// (b) flat load region + one sched_barrier(0) forces all loads to issue
//     before FFT work starts (single pin-point, not per-op pinning).
__global__ __launch_bounds__(256, 2) void k_cols(float2* __restrict__ Yt,
                                                 const int* __restrict__ pk,
                                                 const float* __restrict__ pimp) {
  __shared__ float pilx[128];
  int tid = threadIdx.x;
  int b = blockIdx.x / 33, g = blockIdx.x % 33;
  if (tid < 128) pilx[tid] = (tid < 64) ? pimp[b * 64 + tid] * HALF_INV : HALF_INV;
  int w = tid >> 6, lane = tid & 63;
  int j0 = g * 8 + 2 * w;
  float2* col0 = Yt + ((size_t)b * 264 + j0) * 512;
  float2* col1 = col0 + 512;
  const int* cm0 = pk + j0 * 512;
  const int* cm1 = cm0 + 512;
  float2 A[8], B[8];
  int pcm[16];
  #pragma unroll
  for (int q = 0; q < 8; ++q) A[q] = col0[q * 64 + lane];        // 8x dwordx2
  #pragma unroll
  for (int q = 0; q < 8; ++q) B[q] = col1[q * 64 + lane];        // 8x dwordx2
  #pragma unroll
  for (int q = 0; q < 8; ++q) {                                  // 16x dword
    pcm[q]     = cm0[q * 64 + lane];
    pcm[8 + q] = cm1[q * 64 + lane];
  }
  __builtin_amdgcn_sched_barrier(0);             // all 32 loads issued before any FFT work
  v2f Xr[8], Xi[8];
  #pragma unroll
  for (int q = 0; q < 4; ++q) {
    Xr[q]   = v2(A[2*q].x, A[2*q+1].x); Xi[q]   = v2(A[2*q].y, A[2*q+1].y);
    Xr[4+q] = v2(B[2*q].x, B[2*q+1].x); Xi[4+q] = v2(B[2*q].y, B[2*q+1].y);
  }
  Tw t = make_tw(lane);
  wave_fft512_fwd2(Xr, Xi, lane, t);
  __syncthreads();                               // pilx ready (hidden behind FFT)
  #pragma unroll
  for (int q = 0; q < 8; ++q) {                  // packed symmetrized mask
    int p0 = pcm[2*q], p1 = pcm[2*q+1];
    v2f mv = v2(pilx[p0 & 127] + pilx[(p0 >> 7) & 127],
                pilx[p1 & 127] + pilx[(p1 >> 7) & 127]);
    Xr[q] *= mv; Xi[q] *= mv;
  }
  wave_fft512_inv2(Xr, Xi, lane, t);
  bool live0 = (j0 <= 256), live1 = (j0 + 1 <= 256);   // guard STORES only
  #pragma unroll
  for (int q = 0; q < 4; ++q) {
    if (live0) {
      col0[(2*q)*64 + lane]   = make_float2(Xr[q].x, Xi[q].x);
      col0[(2*q+1)*64 + lane] = make_float2(Xr[q].y, Xi[q].y);
    }
    if (live1) {
      col1[(2*q)*64 + lane]   = make_float2(Xr[4+q].x, Xi[4+q].x);
      col1[(2*q+1)*64 + lane] = make_float2(Xr[4+q].y, Xi[4+q].y);
    }
  }
}

// Hermitian merge folded into the load loop: C = A + iB is written directly
// to the complex tile at FFT input positions; FFT reads are b64 lane-consecutive.
__global__ __launch_bounds__(256) void k_inv_rows(const float2* __restrict__ Yt,
                                                  float* __restrict__ out) {
  __shared__ float2 zc[8][517];
  int tid = threadIdx.x, w = tid >> 6, lane = tid & 63;
  int R0 = blockIdx.x * 16;
  int bb = R0 >> 9, r0 = R0 & 511;
  #pragma unroll
  for (int rep = 0; rep < 9; ++rep) {            // 257*8 (j,f) items; 16B dwordx4 loads
    int e = rep * 256 + tid;
    int j = e >> 3, f = e & 7;
    if (j < 257) {
      const float2* src = &Yt[((size_t)bb * 264 + j) * 512 + r0 + 2 * f];
      float2 a = src[0], b = src[1];             // contiguous 16B -> dwordx4
      float2 ce = make_float2(a.x - b.y, a.y + b.x);     // s = +1 branch
      if (j == 0) {
        zc[f][0] = ce;
      } else if (j == 256) {
        zc[f][1] = ce;
      } else {
        zc[f][2*j] = ce;
        int po = brev9((512 - brev9(2*j)) & 511);        // odd mirror position
        zc[f][po] = make_float2(a.x + b.y, b.x - a.y);   // s = -1 branch
      }
    }
  }
  Tw t = make_tw(lane);
  __syncthreads();
  v2f Xr[8], Xi[8];
  #pragma unroll
  for (int q = 0; q < 4; ++q) {
    float2 c0 = zc[2*w]  [(2*q)*64 + lane];
    float2 c1 = zc[2*w]  [(2*q+1)*64 + lane];
    float2 d0 = zc[2*w+1][(2*q)*64 + lane];
    float2 d1 = zc[2*w+1][(2*q+1)*64 + lane];
    Xr[q]   = v2(c0.x, c1.x); Xi[q]   = v2(c0.y, c1.y);
    Xr[4+q] = v2(d0.x, d1.x); Xi[4+q] = v2(d0.y, d1.y);
  }
  wave_fft512_inv2(Xr, Xi, lane, t);
  float* orA0 = out + (size_t)(R0 + 4 * w) * 512;
  float* orB0 = orA0 + 512;
  float* orA1 = orA0 + 1024;
  float* orB1 = orA0 + 1536;
  #pragma unroll
  for (int q = 0; q < 4; ++q) {
    orA0[(2*q)*64 + lane]   = Xr[q].x;   orA0[(2*q+1)*64 + lane] = Xr[q].y;
    orB0[(2*q)*64 + lane]   = Xi[q].x;   orB0[(2*q+1)*64 + lane] = Xi[q].y;
    orA1[(2*q)*64 + lane]   = Xr[4+q].x; orA1[(2*q+1)*64 + lane] = Xr[4+q].y;
    orB1[(2*q)*64 + lane]   = Xi[4+q].x; orB1[(2*q+1)*64 + lane] = Xi[4+q].y;
  }
}

extern "C" void kernel_launch(void* const* d_in, const int* in_sizes, int n_in,
                              void* d_out, int out_size, void* d_ws, size_t ws_size,
                              hipStream_t stream) {
  const float* x    = (const float*)d_in[0];
  const float* pimp = (const float*)d_in[1];
  const int* idxx   = (const int*)d_in[2];
  const int* idxy   = (const int*)d_in[3];
  const int* cid    = (const int*)d_in[4];

  float2* Yt = (float2*)d_ws;                                    // 69.2 MB
  int* W  = (int*)((char*)d_ws + (size_t)64 * YT_B * sizeof(float2)); // 1 MB
  int* pk = W + 512 * 512;                                       // 0.54 MB

  hipMemsetAsync(W, 0xFF, 512 * 512 * sizeof(int), stream);
  k_fwd_rows <<<2048 + 256, 256, 0, stream>>>(x, Yt,
                                              (const int4*)idxx, (const int4*)idxy,
                                              (const int4*)cid, W);
  k_pack     <<<(264 * 512 + 255) / 256, 256, 0, stream>>>(W, pk);
  k_cols     <<<64 * 33, 256, 0, stream>>>(Yt, pk, pimp);
  k_inv_rows <<<2048, 256, 0, stream>>>(Yt, (float*)d_out);
}